// Round 8
// baseline (954.034 us; speedup 1.0000x reference)
//
#include <hip/hip_runtime.h>

#define B_TOTAL   8192
#define CR_LEN    168
#define PR_LEN    24
#define HID       40
#define ROWS      4           // rows per block
#define NTHREADS  320         // 2 pair-halves * 4 rows * 40 units (5 waves)
#define OUT_STRIDE (B_TOTAL * PR_LEN)   // 196608

__device__ __forceinline__ float fast_rcp(float x) { return __builtin_amdgcn_rcpf(x); }

__device__ __forceinline__ float sigmoid_f(float x) {
    return fast_rcp(1.0f + __expf(-x));
}

__device__ __forceinline__ float tanh_f(float x) {
    float ax = fabsf(x);
    float e  = __expf(-2.0f * ax);
    float r  = (1.0f - e) * fast_rcp(1.0f + e);
    return copysignf(r, x);
}

__device__ __forceinline__ unsigned rotl32(unsigned x, int d) {
    return (x << d) | (x >> (32 - d));
}

// JAX threefry2x32 (20 rounds) — HW-KAT-verified (round 2)
__device__ __forceinline__ void threefry2x32(unsigned k0, unsigned k1,
                                             unsigned c0, unsigned c1,
                                             unsigned& o0, unsigned& o1) {
    const unsigned k2 = 0x1BD11BDAu ^ k0 ^ k1;
    unsigned x0 = c0 + k0, x1 = c1 + k1;
#define TF_R(rr) { x0 += x1; x1 = rotl32(x1, (rr)); x1 ^= x0; }
    TF_R(13) TF_R(15) TF_R(26) TF_R(6)  x0 += k1; x1 += k2 + 1u;
    TF_R(17) TF_R(29) TF_R(16) TF_R(24) x0 += k2; x1 += k0 + 2u;
    TF_R(13) TF_R(15) TF_R(26) TF_R(6)  x0 += k0; x1 += k1 + 3u;
    TF_R(17) TF_R(29) TF_R(16) TF_R(24) x0 += k1; x1 += k2 + 4u;
    TF_R(13) TF_R(15) TF_R(26) TF_R(6)  x0 += k2; x1 += k0 + 5u;
#undef TF_R
    o0 = x0; o1 = x1;
}

// Giles single-precision erfinv (XLA ErfInv32 poly)
__device__ __forceinline__ float erfinv_f(float x) {
    float w = -__logf(fmaf(-x, x, 1.0f));
    float p;
    if (w < 5.0f) {
        w -= 2.5f;
        p = 2.81022636e-08f;
        p = fmaf(p, w, 3.43273939e-07f);
        p = fmaf(p, w, -3.5233877e-06f);
        p = fmaf(p, w, -4.39150654e-06f);
        p = fmaf(p, w, 0.00021858087f);
        p = fmaf(p, w, -0.00125372503f);
        p = fmaf(p, w, -0.00417768164f);
        p = fmaf(p, w, 0.246640727f);
        p = fmaf(p, w, 1.50140941f);
    } else {
        w = sqrtf(w) - 3.0f;
        p = -0.000200214257f;
        p = fmaf(p, w, 0.000100950558f);
        p = fmaf(p, w, 0.00134934322f);
        p = fmaf(p, w, -0.00367342844f);
        p = fmaf(p, w, 0.00573950773f);
        p = fmaf(p, w, -0.0076224613f);
        p = fmaf(p, w, 0.00943887047f);
        p = fmaf(p, w, 1.00167406f);
        p = fmaf(p, w, 2.83297682f);
    }
    return p * x;
}

// KAT tripwire (Random123 vectors)
__device__ __forceinline__ float kat_poison() {
    float poison = 0.0f;
    unsigned o0, o1;
    threefry2x32(0u, 0u, 0u, 0u, o0, o1);
    bool ok1 = (o0 == 0x6b200159u) && (o1 == 0x99ba4efeu);
    threefry2x32(0xFFFFFFFFu, 0xFFFFFFFFu, 0xFFFFFFFFu, 0xFFFFFFFFu, o0, o1);
    bool ok2 = (o0 == 0x1cb996fcu) && (o1 == 0xbb002be7u);
    if (!(ok1 && ok2)) poison += 4096.0f;
    threefry2x32(0x13198a2eu, 0x03707344u, 0x243f6a88u, 0x85a308d3u, o0, o1);
    bool ok3 = (o0 == 0xc4923a9cu) && (o1 == 0x483df7a0u);
    if (!ok3) poison += 8192.0f;
    return poison;
}

// Opaque-pin a loaded quad (param must not be named `w` — R6 lesson).
#define KEEPQ(q) asm volatile("" : "+v"((q).x), "+v"((q).y), "+v"((q).z), "+v"((q).w))

// 4 fma's: acc += dot(w4, h4)
#define DOT4(acc, w4, h4) \
    acc = fmaf((w4).x, (h4).x, acc); acc = fmaf((w4).y, (h4).y, acc); \
    acc = fmaf((w4).z, (h4).z, acc); acc = fmaf((w4).w, (h4).w, acc);

// load 10 named float4 weight quads for one gate row, then pin them
#define LOADW(P, base)                                                         \
    float4 P##0 = pw[(base) + 0], P##1 = pw[(base) + 1],                       \
           P##2 = pw[(base) + 2], P##3 = pw[(base) + 3],                       \
           P##4 = pw[(base) + 4], P##5 = pw[(base) + 5],                       \
           P##6 = pw[(base) + 6], P##7 = pw[(base) + 7],                       \
           P##8 = pw[(base) + 8], P##9 = pw[(base) + 9];                       \
    KEEPQ(P##0); KEEPQ(P##1); KEEPQ(P##2); KEEPQ(P##3); KEEPQ(P##4);           \
    KEEPQ(P##5); KEEPQ(P##6); KEEPQ(P##7); KEEPQ(P##8); KEEPQ(P##9);

// x-path coefficients for one gate (embedding collapsed)
#define XCOEF(g, fAv, fCv, f0v, f1v, f2v) {                                    \
    const int row_ = (g) * HID + j;                                            \
    const float* wr_ = W_ih + row_ * 23;                                       \
    float a_ = 0.0f, cc_ = b_ih[row_] + b_hh[row_];                            \
    _Pragma("unroll")                                                          \
    for (int e = 0; e < 20; e++) {                                             \
        float wv_ = wr_[e];                                                    \
        a_  = fmaf(wv_, W_emb[e], a_);                                         \
        cc_ = fmaf(wv_, b_emb[e], cc_);                                        \
    }                                                                          \
    fAv = a_; fCv = cc_; f0v = wr_[20]; f1v = wr_[21]; f2v = wr_[22];          \
}

// One cell step under the gate-pair decomposition.
// ph==0 threads own gates (i,f); ph==1 own (g,o) and export via ex_s.
#define CELL_STEP(z1n, xa, xb, xv) do {                                        \
    float ae = fmaf(fAe, (z1n), fCe); float af = fmaf(fAf, (z1n), fCf);        \
    ae = fmaf(fp0e, (xa), ae); af = fmaf(fp0f, (xa), af);                      \
    ae = fmaf(fp1e, (xb), ae); af = fmaf(fp1f, (xb), af);                      \
    ae = fmaf(fp2e, (xv), ae); af = fmaf(fp2f, (xv), af);                      \
    const float4* hp = (const float4*)&h_s[cur][r][0];                         \
    float4 h4;                                                                 \
    h4 = hp[0]; DOT4(ae, wE0, h4) DOT4(af, wF0, h4)                            \
    h4 = hp[1]; DOT4(ae, wE1, h4) DOT4(af, wF1, h4)                            \
    h4 = hp[2]; DOT4(ae, wE2, h4) DOT4(af, wF2, h4)                            \
    h4 = hp[3]; DOT4(ae, wE3, h4) DOT4(af, wF3, h4)                            \
    h4 = hp[4]; DOT4(ae, wE4, h4) DOT4(af, wF4, h4)                            \
    h4 = hp[5]; DOT4(ae, wE5, h4) DOT4(af, wF5, h4)                            \
    h4 = hp[6]; DOT4(ae, wE6, h4) DOT4(af, wF6, h4)                            \
    h4 = hp[7]; DOT4(ae, wE7, h4) DOT4(af, wF7, h4)                            \
    h4 = hp[8]; DOT4(ae, wE8, h4) DOT4(af, wF8, h4)                            \
    h4 = hp[9]; DOT4(ae, wE9, h4) DOT4(af, wF9, h4)                            \
    if (ph) { ex_s[r][j] = make_float2(ae, af); }   /* a_g, a_o */             \
    __syncthreads();                                                           \
    if (!ph) {                                                                 \
        float2 exgo = ex_s[r][j];                                              \
        float gi = sigmoid_f(ae);                                              \
        float gf = sigmoid_f(af);                                              \
        float gg = tanh_f(exgo.x);                                             \
        float go = sigmoid_f(exgo.y);                                          \
        c_st = fmaf(gf, c_st, gi * gg);                                        \
        h_s[cur ^ 1][r][j] = go * tanh_f(c_st);                                \
    }                                                                          \
    __syncthreads();                                                           \
    cur ^= 1;                                                                  \
} while (0)

__launch_bounds__(NTHREADS, 1)
__global__ void deepar_kernel(const float* __restrict__ z1,
                              const float* __restrict__ xc,
                              const float* __restrict__ W_emb,
                              const float* __restrict__ b_emb,
                              const float* __restrict__ W_ih,
                              const float* __restrict__ b_ih,
                              const float* __restrict__ W_hh,
                              const float* __restrict__ b_hh,
                              const float* __restrict__ W_mu,
                              const float* __restrict__ b_mu,
                              const float* __restrict__ W_sig,
                              const float* __restrict__ b_sig,
                              float* __restrict__ out) {
    __shared__ __align__(16) float z1_s[ROWS][CR_LEN];
    __shared__ __align__(16) float xc_s[ROWS][(CR_LEN + PR_LEN) * 3];
    __shared__ __align__(16) float h_s[2][ROWS][HID];   // double buffer
    __shared__ float2 ex_s[ROWS][HID];                  // a_g, a_o exchange
    __shared__ float eps_s[ROWS][PR_LEN];
    __shared__ float y_s[ROWS];
    __shared__ __align__(16) float wmu_s[HID];
    __shared__ __align__(16) float wsg_s[HID];
    __shared__ float bmu_s, bsg_s;

    const int tid = threadIdx.x;
    const int ph  = tid / 160;          // 0: gates (i,f) ; 1: gates (g,o)
    const int u   = tid - ph * 160;
    const int r   = u / HID;            // row within block (0..3)
    const int j   = u - r * HID;        // hidden unit (0..39)
    const int b   = blockIdx.x * ROWS + r;   // 2048*4 == 8192: always valid

    // ---- cooperative staging (320 threads, float4) ----
    {
        const float4* s1 = (const float4*)(z1 + (size_t)blockIdx.x * ROWS * CR_LEN);
        float4* d1 = (float4*)&z1_s[0][0];
        for (int idx = tid; idx < ROWS * (CR_LEN / 4); idx += NTHREADS) d1[idx] = s1[idx];
        const float4* s2 = (const float4*)(xc + (size_t)blockIdx.x * ROWS * (CR_LEN + PR_LEN) * 3);
        float4* d2 = (float4*)&xc_s[0][0];
        for (int idx = tid; idx < ROWS * ((CR_LEN + PR_LEN) * 3 / 4); idx += NTHREADS) d2[idx] = s2[idx];
    }
    if (tid < HID)                 wmu_s[tid] = W_mu[tid];
    else if (tid < 2 * HID)        wsg_s[tid - HID] = W_sig[tid - HID];
    else if (tid == 2 * HID)       bmu_s = b_mu[0];
    else if (tid == 2 * HID + 1)   bsg_s = b_sig[0];

    // ---- x-path coefficients for my two gates (named scalars) ----
    float fAe, fCe, fp0e, fp1e, fp2e;
    float fAf, fCf, fp0f, fp1f, fp2f;
    XCOEF(2 * ph,     fAe, fCe, fp0e, fp1e, fp2e)
    XCOEF(2 * ph + 1, fAf, fCf, fp0f, fp1f, fp2f)

    // ---- my two gate rows of W_hh: 20 pinned float4 (80 VGPRs) ----
    const float4* pw = (const float4*)W_hh;
    LOADW(wE, ((2 * ph) * HID + j) * 10)
    LOADW(wF, ((2 * ph + 1) * HID + j) * 10)

    __syncthreads();   // staging ready

    // ---- v = mean(z1)+1 (broadcast reads) ----
    float s = 0.0f;
#pragma unroll
    for (int q = 0; q < CR_LEN / 4; q++) {
        float4 zz = *(const float4*)&z1_s[r][4 * q];
        s += zz.x + zz.y + zz.z + zz.w;
    }
    const float v = s * (1.0f / (float)CR_LEN) + 1.0f;
    const float inv_v = 1.0f / v;

    // eps: JAX threefry PARTITIONABLE path (verified R3): ctr=(0,i), bits=o0^o1
    if (ph == 0 && j < PR_LEN) {
        unsigned i = (unsigned)j * B_TOTAL + (unsigned)b;
        unsigned o0, o1;
        threefry2x32(0u, 42u, 0u, i, o0, o1);
        unsigned bits = o0 ^ o1;
        float f = __uint_as_float((bits >> 9) | 0x3F800000u) - 1.0f;
        const float lo = -0.99999994f;
        float uu = fmaxf(lo, fmaf(f, 2.0f, lo));
        eps_s[r][j] = 1.41421356237f * erfinv_f(uu);
    }

    if (ph == 0) h_s[0][r][j] = 0.0f;
    float c_st = 0.0f;
    __syncthreads();

    int cur = 0;

    // ---- conditioning: t = 0..166 ----
    for (int t = 0; t < CR_LEN - 1; t++) {
        float z1n = z1_s[r][t] * inv_v;
        float xa = xc_s[r][3 * (t + 1) + 0];
        float xb = xc_s[r][3 * (t + 1) + 1];
        float xv = xc_s[r][3 * (t + 1) + 2];
        CELL_STEP(z1n, xa, xb, xv);
    }

    if (ph == 0 && j == 0) y_s[r] = z1_s[r][CR_LEN - 1];
    __syncthreads();

    // ---- prediction: t = 0..23 ----
    for (int t = 0; t < PR_LEN; t++) {
        float z1n = y_s[r] * inv_v;
        float xa = xc_s[r][3 * (CR_LEN + t) + 0];
        float xb = xc_s[r][3 * (CR_LEN + t) + 1];
        float xv = xc_s[r][3 * (CR_LEN + t) + 2];
        CELL_STEP(z1n, xa, xb, xv);
        if (ph == 0 && j == 0) {
            float mu = bmu_s, sp = bsg_s;
#pragma unroll
            for (int q = 0; q < 10; q++) {
                float4 h4 = *(const float4*)&h_s[cur][r][4 * q];
                float4 wm = *(const float4*)&wmu_s[4 * q];
                float4 ws = *(const float4*)&wsg_s[4 * q];
                mu = fmaf(wm.x, h4.x, mu); mu = fmaf(wm.y, h4.y, mu);
                mu = fmaf(wm.z, h4.z, mu); mu = fmaf(wm.w, h4.w, mu);
                sp = fmaf(ws.x, h4.x, sp); sp = fmaf(ws.y, h4.y, sp);
                sp = fmaf(ws.z, h4.z, sp); sp = fmaf(ws.w, h4.w, sp);
            }
            float sigma = fmaxf(sp, 0.0f) + log1pf(__expf(-fabsf(sp)));
            float y = fmaf(sigma, eps_s[r][t], mu);
            y_s[r] = y;
            const int ob = b * PR_LEN + t;
            float poison = (b == 0 && t == 0) ? kat_poison() : 0.0f;
            out[ob]                  = y * v + poison;
            out[OUT_STRIDE + ob]     = mu * v;
            out[2 * OUT_STRIDE + ob] = sigma * v;
        }
        __syncthreads();   // y_s ready for next step
    }
}

extern "C" void kernel_launch(void* const* d_in, const int* in_sizes, int n_in,
                              void* d_out, int out_size, void* d_ws, size_t ws_size,
                              hipStream_t stream) {
    const float* z1    = (const float*)d_in[0];
    const float* xc    = (const float*)d_in[1];
    const float* W_emb = (const float*)d_in[2];
    const float* b_emb = (const float*)d_in[3];
    const float* W_ih  = (const float*)d_in[4];
    const float* b_ih  = (const float*)d_in[5];
    const float* W_hh  = (const float*)d_in[6];
    const float* b_hh  = (const float*)d_in[7];
    const float* W_mu  = (const float*)d_in[8];
    const float* b_mu  = (const float*)d_in[9];
    const float* W_sig = (const float*)d_in[10];
    const float* b_sig = (const float*)d_in[11];
    float* out = (float*)d_out;

    dim3 grid(B_TOTAL / ROWS);   // 2048
    dim3 block(NTHREADS);        // 320
    deepar_kernel<<<grid, block, 0, stream>>>(z1, xc, W_emb, b_emb, W_ih, b_ih,
                                              W_hh, b_hh, W_mu, b_mu, W_sig, b_sig,
                                              out);
}

// Round 9
// 786.660 us; speedup vs baseline: 1.2128x; 1.2128x over previous
//
#include <hip/hip_runtime.h>

#define B_TOTAL   8192
#define CR_LEN    168
#define PR_LEN    24
#define HID       40
#define ROWS      8            // rows per block (2 engines x 4)
#define NTHREADS  320          // 2 engines x 4 gates x 40 units = 5 full waves
#define XC_LEN    ((CR_LEN + PR_LEN) * 3)   // 576
#define OUT_STRIDE (B_TOTAL * PR_LEN)       // 196608

__device__ __forceinline__ float fast_rcp(float x) { return __builtin_amdgcn_rcpf(x); }

__device__ __forceinline__ float sigmoid_f(float x) {
    return fast_rcp(1.0f + __expf(-x));
}

__device__ __forceinline__ float tanh_f(float x) {
    float ax = fabsf(x);
    float e  = __expf(-2.0f * ax);
    float r  = (1.0f - e) * fast_rcp(1.0f + e);
    return copysignf(r, x);
}

__device__ __forceinline__ unsigned rotl32(unsigned x, int d) {
    return (x << d) | (x >> (32 - d));
}

// JAX threefry2x32 (20 rounds) — HW-KAT-verified (round 2)
__device__ __forceinline__ void threefry2x32(unsigned k0, unsigned k1,
                                             unsigned c0, unsigned c1,
                                             unsigned& o0, unsigned& o1) {
    const unsigned k2 = 0x1BD11BDAu ^ k0 ^ k1;
    unsigned x0 = c0 + k0, x1 = c1 + k1;
#define TF_R(rr) { x0 += x1; x1 = rotl32(x1, (rr)); x1 ^= x0; }
    TF_R(13) TF_R(15) TF_R(26) TF_R(6)  x0 += k1; x1 += k2 + 1u;
    TF_R(17) TF_R(29) TF_R(16) TF_R(24) x0 += k2; x1 += k0 + 2u;
    TF_R(13) TF_R(15) TF_R(26) TF_R(6)  x0 += k0; x1 += k1 + 3u;
    TF_R(17) TF_R(29) TF_R(16) TF_R(24) x0 += k1; x1 += k2 + 4u;
    TF_R(13) TF_R(15) TF_R(26) TF_R(6)  x0 += k2; x1 += k0 + 5u;
#undef TF_R
    o0 = x0; o1 = x1;
}

// Giles single-precision erfinv (XLA ErfInv32 poly)
__device__ __forceinline__ float erfinv_f(float x) {
    float w = -__logf(fmaf(-x, x, 1.0f));
    float p;
    if (w < 5.0f) {
        w -= 2.5f;
        p = 2.81022636e-08f;
        p = fmaf(p, w, 3.43273939e-07f);
        p = fmaf(p, w, -3.5233877e-06f);
        p = fmaf(p, w, -4.39150654e-06f);
        p = fmaf(p, w, 0.00021858087f);
        p = fmaf(p, w, -0.00125372503f);
        p = fmaf(p, w, -0.00417768164f);
        p = fmaf(p, w, 0.246640727f);
        p = fmaf(p, w, 1.50140941f);
    } else {
        w = sqrtf(w) - 3.0f;
        p = -0.000200214257f;
        p = fmaf(p, w, 0.000100950558f);
        p = fmaf(p, w, 0.00134934322f);
        p = fmaf(p, w, -0.00367342844f);
        p = fmaf(p, w, 0.00573950773f);
        p = fmaf(p, w, -0.0076224613f);
        p = fmaf(p, w, 0.00943887047f);
        p = fmaf(p, w, 1.00167406f);
        p = fmaf(p, w, 2.83297682f);
    }
    return p * x;
}

// KAT tripwire (Random123 vectors)
__device__ __forceinline__ float kat_poison() {
    float poison = 0.0f;
    unsigned o0, o1;
    threefry2x32(0u, 0u, 0u, 0u, o0, o1);
    bool ok1 = (o0 == 0x6b200159u) && (o1 == 0x99ba4efeu);
    threefry2x32(0xFFFFFFFFu, 0xFFFFFFFFu, 0xFFFFFFFFu, 0xFFFFFFFFu, o0, o1);
    bool ok2 = (o0 == 0x1cb996fcu) && (o1 == 0xbb002be7u);
    if (!(ok1 && ok2)) poison += 4096.0f;
    threefry2x32(0x13198a2eu, 0x03707344u, 0x243f6a88u, 0x85a308d3u, o0, o1);
    bool ok3 = (o0 == 0xc4923a9cu) && (o1 == 0x483df7a0u);
    if (!ok3) poison += 8192.0f;
    return poison;
}

// Opaque-pin a loaded quad (param must not be named `w` — R6 lesson).
#define KEEPQ(q) asm volatile("" : "+v"((q).x), "+v"((q).y), "+v"((q).z), "+v"((q).w))

// 4 fma's: acc += dot(w4, h4)
#define DOT4(acc, w4, h4) \
    acc = fmaf((w4).x, (h4).x, acc); acc = fmaf((w4).y, (h4).y, acc); \
    acc = fmaf((w4).z, (h4).z, acc); acc = fmaf((w4).w, (h4).w, acc);

// matvec for one of this thread's 4 rows: gate-g pre-activation, full k
#define MVROW(rr, ZN, XOFF) do {                                               \
    const int row_ = ebase + (rr);                                             \
    const float* xp_ = &xc_s[row_][XOFF];                                      \
    float acc_ = fmaf(fA, (ZN), fC);                                           \
    acc_ = fmaf(f0, xp_[0], acc_);                                             \
    acc_ = fmaf(f1, xp_[1], acc_);                                             \
    acc_ = fmaf(f2, xp_[2], acc_);                                             \
    const float4* hp_ = (const float4*)&h_s[cur][row_][0];                     \
    float4 h4_;                                                                \
    h4_ = hp_[0]; DOT4(acc_, wq0, h4_)                                         \
    h4_ = hp_[1]; DOT4(acc_, wq1, h4_)                                         \
    h4_ = hp_[2]; DOT4(acc_, wq2, h4_)                                         \
    h4_ = hp_[3]; DOT4(acc_, wq3, h4_)                                         \
    h4_ = hp_[4]; DOT4(acc_, wq4, h4_)                                         \
    h4_ = hp_[5]; DOT4(acc_, wq5, h4_)                                         \
    h4_ = hp_[6]; DOT4(acc_, wq6, h4_)                                         \
    h4_ = hp_[7]; DOT4(acc_, wq7, h4_)                                         \
    h4_ = hp_[8]; DOT4(acc_, wq8, h4_)                                         \
    h4_ = hp_[9]; DOT4(acc_, wq9, h4_)                                         \
    pre_s[row_][g][j] = acc_;                                                  \
} while (0)

// fully-parallel cell update: this thread owns (row_up, j)
#define UPDATE() do {                                                          \
    float ai_ = pre_s[row_up][0][j];                                           \
    float af_ = pre_s[row_up][1][j];                                           \
    float ag_ = pre_s[row_up][2][j];                                           \
    float ao_ = pre_s[row_up][3][j];                                           \
    float gi_ = sigmoid_f(ai_);                                                \
    float gf_ = sigmoid_f(af_);                                                \
    float gg_ = tanh_f(ag_);                                                   \
    float go_ = sigmoid_f(ao_);                                                \
    c_st = fmaf(gf_, c_st, gi_ * gg_);                                         \
    h_s[cur ^ 1][row_up][j] = go_ * tanh_f(c_st);                              \
} while (0)

__launch_bounds__(NTHREADS, 4)
__global__ void deepar_kernel(const float* __restrict__ z1,
                              const float* __restrict__ xc,
                              const float* __restrict__ W_emb,
                              const float* __restrict__ b_emb,
                              const float* __restrict__ W_ih,
                              const float* __restrict__ b_ih,
                              const float* __restrict__ W_hh,
                              const float* __restrict__ b_hh,
                              const float* __restrict__ W_mu,
                              const float* __restrict__ b_mu,
                              const float* __restrict__ W_sig,
                              const float* __restrict__ b_sig,
                              float* __restrict__ out) {
    __shared__ __align__(16) float z1_s[ROWS][CR_LEN];
    __shared__ __align__(16) float xc_s[ROWS][XC_LEN];
    __shared__ __align__(16) float h_s[2][ROWS][HID];
    __shared__ __align__(16) float pre_s[ROWS][4][HID];
    __shared__ float eps_s[ROWS][PR_LEN];
    __shared__ float y_s[ROWS];
    __shared__ float v_s[ROWS], iv_s[ROWS];
    __shared__ __align__(16) float wmu_s[HID];
    __shared__ __align__(16) float wsg_s[HID];
    __shared__ float bmu_s, bsg_s;

    const int tid   = threadIdx.x;
    const int e     = tid / 160;        // engine: 0 or 1
    const int u     = tid - e * 160;
    const int g     = u / HID;          // gate 0..3 (i,f,g,o)
    const int j     = u - g * HID;      // unit 0..39
    const int ebase = e * 4;            // engine's first row in block
    const int row_up = ebase + g;       // (row, j) this thread updates
    const int b_base = blockIdx.x * ROWS;

    // ---- cooperative staging ----
    {
        const float4* s1 = (const float4*)(z1 + (size_t)b_base * CR_LEN);
        float4* d1 = (float4*)&z1_s[0][0];
        for (int idx = tid; idx < ROWS * (CR_LEN / 4); idx += NTHREADS) d1[idx] = s1[idx];
        const float4* s2 = (const float4*)(xc + (size_t)b_base * XC_LEN);
        float4* d2 = (float4*)&xc_s[0][0];
        for (int idx = tid; idx < ROWS * (XC_LEN / 4); idx += NTHREADS) d2[idx] = s2[idx];
    }
    if (tid < HID)                 wmu_s[tid] = W_mu[tid];
    else if (tid < 2 * HID)        wsg_s[tid - HID] = W_sig[tid - HID];
    else if (tid == 2 * HID)       bmu_s = b_mu[0];
    else if (tid == 2 * HID + 1)   bsg_s = b_sig[0];

    // ---- x-path coefficients for my gate row (g*HID + j) ----
    float fA, fC, f0, f1, f2;
    {
        const int row_ = g * HID + j;
        const float* wr_ = W_ih + row_ * 23;
        float a_ = 0.0f, cc_ = b_ih[row_] + b_hh[row_];
#pragma unroll
        for (int ee = 0; ee < 20; ee++) {
            float wv_ = wr_[ee];
            a_  = fmaf(wv_, W_emb[ee], a_);
            cc_ = fmaf(wv_, b_emb[ee], cc_);
        }
        fA = a_; fC = cc_; f0 = wr_[20]; f1 = wr_[21]; f2 = wr_[22];
    }

    // ---- my W_hh gate row: 10 pinned float4 (40 VGPRs) ----
    const float4* pw = (const float4*)W_hh;
    const int wbase = (g * HID + j) * 10;
    float4 wq0 = pw[wbase + 0], wq1 = pw[wbase + 1], wq2 = pw[wbase + 2],
           wq3 = pw[wbase + 3], wq4 = pw[wbase + 4], wq5 = pw[wbase + 5],
           wq6 = pw[wbase + 6], wq7 = pw[wbase + 7], wq8 = pw[wbase + 8],
           wq9 = pw[wbase + 9];
    KEEPQ(wq0); KEEPQ(wq1); KEEPQ(wq2); KEEPQ(wq3); KEEPQ(wq4);
    KEEPQ(wq5); KEEPQ(wq6); KEEPQ(wq7); KEEPQ(wq8); KEEPQ(wq9);

    __syncthreads();   // staging ready

    // ---- v per row (threads 0..7) ----
    if (tid < ROWS) {
        float s = 0.0f;
#pragma unroll
        for (int q = 0; q < CR_LEN / 4; q++) {
            float4 zz = *(const float4*)&z1_s[tid][4 * q];
            s += zz.x + zz.y + zz.z + zz.w;
        }
        float v = s * (1.0f / (float)CR_LEN) + 1.0f;
        v_s[tid]  = v;
        iv_s[tid] = 1.0f / v;
    }

    // ---- eps (threads 0..191): row=tid/24, tt=tid%24 ----
    if (tid < ROWS * PR_LEN) {
        const int row_ = tid / PR_LEN;
        const int tt   = tid - row_ * PR_LEN;
        unsigned i = (unsigned)tt * B_TOTAL + (unsigned)(b_base + row_);
        unsigned o0, o1;
        threefry2x32(0u, 42u, 0u, i, o0, o1);
        unsigned bits = o0 ^ o1;
        float f = __uint_as_float((bits >> 9) | 0x3F800000u) - 1.0f;
        const float lo = -0.99999994f;
        float uu = fmaxf(lo, fmaf(f, 2.0f, lo));
        eps_s[row_][tt] = 1.41421356237f * erfinv_f(uu);
    }

    h_s[0][row_up][j] = 0.0f;   // 320 threads cover all 8x40 exactly
    float c_st = 0.0f;
    __syncthreads();

    const float iv0 = iv_s[ebase + 0], iv1 = iv_s[ebase + 1],
                iv2 = iv_s[ebase + 2], iv3 = iv_s[ebase + 3];
    int cur = 0;

    // ---- conditioning: t = 0..166 ----
    for (int t = 0; t < CR_LEN - 1; t++) {
        const int xo = 3 * (t + 1);
        MVROW(0, z1_s[ebase + 0][t] * iv0, xo);
        MVROW(1, z1_s[ebase + 1][t] * iv1, xo);
        MVROW(2, z1_s[ebase + 2][t] * iv2, xo);
        MVROW(3, z1_s[ebase + 3][t] * iv3, xo);
        __syncthreads();
        UPDATE();
        __syncthreads();
        cur ^= 1;
    }

    if (j == 0) y_s[row_up] = z1_s[row_up][CR_LEN - 1];   // 8 threads cover rows
    __syncthreads();

    // ---- prediction: t = 0..23 ----
    for (int t = 0; t < PR_LEN; t++) {
        const int xo = 3 * (CR_LEN + t);
        MVROW(0, y_s[ebase + 0] * iv0, xo);
        MVROW(1, y_s[ebase + 1] * iv1, xo);
        MVROW(2, y_s[ebase + 2] * iv2, xo);
        MVROW(3, y_s[ebase + 3] * iv3, xo);
        __syncthreads();
        UPDATE();
        __syncthreads();
        if (j == 0) {   // 8 threads: one per row
            const int bglob = b_base + row_up;
            float mu = bmu_s, sp = bsg_s;
            const float4* hp = (const float4*)&h_s[cur ^ 1][row_up][0];
#pragma unroll
            for (int q = 0; q < 10; q++) {
                float4 h4 = hp[q];
                float4 wm = *(const float4*)&wmu_s[4 * q];
                float4 ws = *(const float4*)&wsg_s[4 * q];
                mu = fmaf(wm.x, h4.x, mu); mu = fmaf(wm.y, h4.y, mu);
                mu = fmaf(wm.z, h4.z, mu); mu = fmaf(wm.w, h4.w, mu);
                sp = fmaf(ws.x, h4.x, sp); sp = fmaf(ws.y, h4.y, sp);
                sp = fmaf(ws.z, h4.z, sp); sp = fmaf(ws.w, h4.w, sp);
            }
            float sigma = fmaxf(sp, 0.0f) + log1pf(__expf(-fabsf(sp)));
            float y = fmaf(sigma, eps_s[row_up][t], mu);
            y_s[row_up] = y;
            const float v = v_s[row_up];
            const int ob = bglob * PR_LEN + t;
            float poison = (bglob == 0 && t == 0) ? kat_poison() : 0.0f;
            out[ob]                  = y * v + poison;
            out[OUT_STRIDE + ob]     = mu * v;
            out[2 * OUT_STRIDE + ob] = sigma * v;
        }
        __syncthreads();   // y_s ready for next step
        cur ^= 1;
    }
}

extern "C" void kernel_launch(void* const* d_in, const int* in_sizes, int n_in,
                              void* d_out, int out_size, void* d_ws, size_t ws_size,
                              hipStream_t stream) {
    const float* z1    = (const float*)d_in[0];
    const float* xc    = (const float*)d_in[1];
    const float* W_emb = (const float*)d_in[2];
    const float* b_emb = (const float*)d_in[3];
    const float* W_ih  = (const float*)d_in[4];
    const float* b_ih  = (const float*)d_in[5];
    const float* W_hh  = (const float*)d_in[6];
    const float* b_hh  = (const float*)d_in[7];
    const float* W_mu  = (const float*)d_in[8];
    const float* b_mu  = (const float*)d_in[9];
    const float* W_sig = (const float*)d_in[10];
    const float* b_sig = (const float*)d_in[11];
    float* out = (float*)d_out;

    dim3 grid(B_TOTAL / ROWS);   // 1024
    dim3 block(NTHREADS);        // 320
    deepar_kernel<<<grid, block, 0, stream>>>(z1, xc, W_emb, b_emb, W_ih, b_ih,
                                              W_hh, b_hh, W_mu, b_mu, W_sig, b_sig,
                                              out);
}